// Round 1
// baseline (340.000 us; speedup 1.0000x reference)
//
#include <hip/hip_runtime.h>

// Problem constants (fixed by reference setup_inputs)
#define N_CAR   180000
#define N_NODES 200000
#define NE      6400000
#define P_ELEMS (4096 * 4096)

// d_ws layout: float acc[8] then int segmax[N_CAR]
// acc: 0=bce_sum 1=mse_sum 2=viol_cnt 3=rattn_sum 4=gat_sum 5=gat_cnt 6=reg_sum

__device__ __forceinline__ float wave_reduce_sum(float s) {
#pragma unroll
    for (int off = 32; off > 0; off >>= 1) s += __shfl_down(s, off, 64);
    return s;
}

__global__ void __launch_bounds__(256) init_kernel(float* __restrict__ acc,
                                                   int* __restrict__ segmax) {
    int i = blockIdx.x * blockDim.x + threadIdx.x;
    if (i < 8) acc[i] = 0.0f;
    int stride = gridDim.x * blockDim.x;
    for (int j = i; j < N_CAR; j += stride)
        segmax[j] = (int)0xFF800000u;  // -inf bit pattern
}

__global__ void __launch_bounds__(256) edge_kernel(const int* __restrict__ src,
                                                   const int* __restrict__ dst,
                                                   const int* __restrict__ types,
                                                   const float* __restrict__ alpha,
                                                   int* __restrict__ segmax) {
    int e = blockIdx.x * blockDim.x + threadIdx.x;
    if (e >= NE) return;
    int d = dst[e];
    if (types[d] != 0) {            // rule edge: dst is light (1) or stop (2)
        int s = src[e];
        if (s < N_CAR) {            // only car sources matter downstream
            // all alphas >= 0, so signed-int max == float max vs -inf init
            atomicMax(&segmax[s], __float_as_int(alpha[e]));
        }
    }
}

__global__ void __launch_bounds__(256) car_kernel(const float* __restrict__ ms,
                                                  const float* __restrict__ rs,
                                                  const float* __restrict__ beta,
                                                  const int* __restrict__ segmax,
                                                  float* __restrict__ acc) {
    int i = blockIdx.x * blockDim.x + threadIdx.x;
    float vals[6] = {0.f, 0.f, 0.f, 0.f, 0.f, 0.f};
    if (i < N_CAR) {
        float x = ms[i];
        float t = rs[i];
        float lx  = fmaxf(logf(x), -100.0f);
        float l1x = fmaxf(log1pf(-x), -100.0f);
        vals[0] = -(t * lx + (1.0f - t) * l1x);        // bce term
        float df = x - t;
        vals[1] = df * df;                              // mse term
        if (t > 0.5f) {                                 // violation
            vals[2] = 1.0f;
            float b = beta[i];
            vals[3] = (1.0f - b) * (1.0f - b);          // rule-attn term
            float m = __int_as_float(segmax[i]);
            if (m >= 0.0f) {                            // finite seg-max (had rule edge)
                vals[4] = (1.0f - m) * (1.0f - m);      // gat term
                vals[5] = 1.0f;
            }
        }
    }
    __shared__ float red[4][6];
    int wave = threadIdx.x >> 6;
    int lane = threadIdx.x & 63;
#pragma unroll
    for (int k = 0; k < 6; ++k) {
        float s = wave_reduce_sum(vals[k]);
        if (lane == 0) red[wave][k] = s;
    }
    __syncthreads();
    if (threadIdx.x == 0) {
#pragma unroll
        for (int k = 0; k < 6; ++k) {
            float s = red[0][k] + red[1][k] + red[2][k] + red[3][k];
            atomicAdd(&acc[k], s);
        }
    }
}

__global__ void __launch_bounds__(256) reg_kernel(const float4* __restrict__ p0,
                                                  const float4* __restrict__ p1,
                                                  float* __restrict__ acc) {
    const int n4 = P_ELEMS / 4;
    int stride = gridDim.x * blockDim.x;
    float s = 0.0f;
    for (int i = blockIdx.x * blockDim.x + threadIdx.x; i < n4; i += stride) {
        float4 a = p0[i];
        s += a.x * a.x + a.y * a.y + a.z * a.z + a.w * a.w;
        float4 b = p1[i];
        s += b.x * b.x + b.y * b.y + b.z * b.z + b.w * b.w;
    }
    s = wave_reduce_sum(s);
    __shared__ float red[4];
    int wave = threadIdx.x >> 6;
    int lane = threadIdx.x & 63;
    if (lane == 0) red[wave] = s;
    __syncthreads();
    if (threadIdx.x == 0)
        atomicAdd(&acc[6], red[0] + red[1] + red[2] + red[3]);
}

__global__ void finalize_kernel(const float* __restrict__ acc, float* __restrict__ out) {
    if (threadIdx.x != 0 || blockIdx.x != 0) return;
    const float inv_ncar = 1.0f / (float)N_CAR;
    float L_recon = acc[0] * inv_ncar;
    float L_rule  = acc[1] * inv_ncar;
    float vc      = acc[2];
    float L_attn_rule = (vc > 0.0f) ? acc[3] / vc : 0.0f;
    float gat_cnt = acc[5];
    float L_attn_gat = (vc > 0.0f && gat_cnt > 0.0f) ? acc[4] / gat_cnt : 0.0f;
    float L_attn = 0.5f * L_attn_gat + 0.5f * L_attn_rule;
    float L_reg  = acc[6];
    float L_total = 1.0f * L_recon + 0.5f * L_rule + 0.3f * L_attn + 1e-4f * L_reg;
    out[0] = L_total;
    out[1] = L_recon;
    out[2] = L_rule;
    out[3] = L_attn;
    out[4] = L_attn_gat;
    out[5] = L_attn_rule;
    out[6] = L_reg;
    out[7] = vc;
}

extern "C" void kernel_launch(void* const* d_in, const int* in_sizes, int n_in,
                              void* d_out, int out_size, void* d_ws, size_t ws_size,
                              hipStream_t stream) {
    const float* model_scores = (const float*)d_in[0];
    const float* rule_scores  = (const float*)d_in[1];
    const float* alpha_gat    = (const float*)d_in[2];
    const float* beta_rule    = (const float*)d_in[3];
    const int*   edge_index   = (const int*)d_in[4];   // [2, E]: src then dst
    const int*   entity_types = (const int*)d_in[5];
    const float* param0       = (const float*)d_in[6];
    const float* param1       = (const float*)d_in[7];
    float* out = (float*)d_out;

    float* acc    = (float*)d_ws;
    int*   segmax = (int*)d_ws + 8;

    const int* src = edge_index;
    const int* dst = edge_index + NE;

    init_kernel<<<(N_CAR + 255) / 256, 256, 0, stream>>>(acc, segmax);
    edge_kernel<<<(NE + 255) / 256, 256, 0, stream>>>(src, dst, entity_types,
                                                      alpha_gat, segmax);
    car_kernel<<<(N_CAR + 255) / 256, 256, 0, stream>>>(model_scores, rule_scores,
                                                        beta_rule, segmax, acc);
    reg_kernel<<<4096, 256, 0, stream>>>((const float4*)param0, (const float4*)param1, acc);
    finalize_kernel<<<1, 64, 0, stream>>>(acc, out);
}

// Round 2
// 289.702 us; speedup vs baseline: 1.1736x; 1.1736x over previous
//
#include <hip/hip_runtime.h>

// Problem constants (fixed by reference setup_inputs)
#define N_CAR   180000
#define N_NODES 200000
#define NE      6400000
#define P_ELEMS (4096 * 4096)
#define P4      (P_ELEMS / 4)          // 4,194,304 float4 per param

// mega-kernel partition: groups of 4 blocks -> slot0 = reg, slots1-3 = edge
#define REG_BLOCKS   2048
#define REG_THREADS  (REG_BLOCKS * 256)  // 524288
#define REG_ITERS    8                    // P4 / REG_THREADS == 8 exactly
#define EDGE_BLOCKS  6250                 // 6250*256*4 = 6,400,000 edges
#define GROUPS       2084                 // 3*GROUPS >= EDGE_BLOCKS, GROUPS >= REG_BLOCKS
#define MEGA_GRID    (GROUPS * 4)

// d_ws layout: float acc[8] then int segmax[N_CAR] (16B aligned)
// acc: 0=bce_sum 1=mse_sum 2=viol_cnt 3=rattn_sum 4=gat_sum 5=gat_cnt 6=reg_sum

__device__ __forceinline__ float wave_reduce_sum(float s) {
#pragma unroll
    for (int off = 32; off > 0; off >>= 1) s += __shfl_down(s, off, 64);
    return s;
}

__global__ void __launch_bounds__(256) init_kernel(float* __restrict__ acc,
                                                   int4* __restrict__ segmax4) {
    int i = blockIdx.x * blockDim.x + threadIdx.x;
    if (i < 8) acc[i] = 0.0f;
    const int NINF = (int)0xFF800000u;  // -inf bit pattern
    const int n4 = N_CAR / 4;           // 45000
    if (i < n4) segmax4[i] = make_int4(NINF, NINF, NINF, NINF);
}

__global__ void __launch_bounds__(256) mega_kernel(const int4* __restrict__ src4,
                                                   const int4* __restrict__ dst4,
                                                   const int* __restrict__ types,
                                                   const float4* __restrict__ alpha4,
                                                   int* __restrict__ segmax,
                                                   const float4* __restrict__ p0,
                                                   const float4* __restrict__ p1,
                                                   float* __restrict__ acc) {
    int g    = blockIdx.x >> 2;
    int slot = blockIdx.x & 3;
    if (slot == 0) {
        // ---------------- reg part: sum of squares of p0, p1 ----------------
        if (g >= REG_BLOCKS) return;
        int t = g * 256 + threadIdx.x;   // < REG_THREADS
        float s = 0.0f;
        float4 v[REG_ITERS];
#pragma unroll
        for (int k = 0; k < REG_ITERS; ++k) v[k] = p0[t + k * REG_THREADS];
#pragma unroll
        for (int k = 0; k < REG_ITERS; ++k)
            s += v[k].x * v[k].x + v[k].y * v[k].y + v[k].z * v[k].z + v[k].w * v[k].w;
#pragma unroll
        for (int k = 0; k < REG_ITERS; ++k) v[k] = p1[t + k * REG_THREADS];
#pragma unroll
        for (int k = 0; k < REG_ITERS; ++k)
            s += v[k].x * v[k].x + v[k].y * v[k].y + v[k].z * v[k].z + v[k].w * v[k].w;
        s = wave_reduce_sum(s);
        __shared__ float red[4];
        int wave = threadIdx.x >> 6;
        int lane = threadIdx.x & 63;
        if (lane == 0) red[wave] = s;
        __syncthreads();
        if (threadIdx.x == 0)
            atomicAdd(&acc[6], red[0] + red[1] + red[2] + red[3]);
    } else {
        // ---------------- edge part: segment max over car sources ----------------
        int eb = 3 * g + (slot - 1);     // edge block id
        if (eb >= EDGE_BLOCKS) return;
        int t = eb * 256 + threadIdx.x;  // edge quad index, < 1,600,000
        // issue all independent loads up front for MLP
        int4   d = dst4[t];
        int4   sv = src4[t];
        float4 a = alpha4[t];
        int t0 = types[d.x];
        int t1 = types[d.y];
        int t2 = types[d.z];
        int t3 = types[d.w];
        // all alphas >= 0 -> positive int bit patterns; signed max vs -inf init
        if (t0 != 0 && sv.x < N_CAR) atomicMax(&segmax[sv.x], __float_as_int(a.x));
        if (t1 != 0 && sv.y < N_CAR) atomicMax(&segmax[sv.y], __float_as_int(a.y));
        if (t2 != 0 && sv.z < N_CAR) atomicMax(&segmax[sv.z], __float_as_int(a.z));
        if (t3 != 0 && sv.w < N_CAR) atomicMax(&segmax[sv.w], __float_as_int(a.w));
    }
}

__global__ void __launch_bounds__(256) car_kernel(const float* __restrict__ ms,
                                                  const float* __restrict__ rs,
                                                  const float* __restrict__ beta,
                                                  const int* __restrict__ segmax,
                                                  float* __restrict__ acc) {
    int i = blockIdx.x * blockDim.x + threadIdx.x;
    float vals[6] = {0.f, 0.f, 0.f, 0.f, 0.f, 0.f};
    if (i < N_CAR) {
        float x = ms[i];
        float t = rs[i];
        float lx  = fmaxf(logf(x), -100.0f);
        float l1x = fmaxf(log1pf(-x), -100.0f);
        vals[0] = -(t * lx + (1.0f - t) * l1x);        // bce term
        float df = x - t;
        vals[1] = df * df;                              // mse term
        if (t > 0.5f) {                                 // violation
            vals[2] = 1.0f;
            float b = beta[i];
            vals[3] = (1.0f - b) * (1.0f - b);          // rule-attn term
            float m = __int_as_float(segmax[i]);
            if (m >= 0.0f) {                            // had a rule edge
                vals[4] = (1.0f - m) * (1.0f - m);      // gat term
                vals[5] = 1.0f;
            }
        }
    }
    __shared__ float red[4][6];
    int wave = threadIdx.x >> 6;
    int lane = threadIdx.x & 63;
#pragma unroll
    for (int k = 0; k < 6; ++k) {
        float s = wave_reduce_sum(vals[k]);
        if (lane == 0) red[wave][k] = s;
    }
    __syncthreads();
    if (threadIdx.x == 0) {
#pragma unroll
        for (int k = 0; k < 6; ++k)
            atomicAdd(&acc[k], red[0][k] + red[1][k] + red[2][k] + red[3][k]);
    }
}

__global__ void finalize_kernel(const float* __restrict__ acc, float* __restrict__ out) {
    if (threadIdx.x != 0 || blockIdx.x != 0) return;
    const float inv_ncar = 1.0f / (float)N_CAR;
    float L_recon = acc[0] * inv_ncar;
    float L_rule  = acc[1] * inv_ncar;
    float vc      = acc[2];
    float L_attn_rule = (vc > 0.0f) ? acc[3] / vc : 0.0f;
    float gat_cnt = acc[5];
    float L_attn_gat = (vc > 0.0f && gat_cnt > 0.0f) ? acc[4] / gat_cnt : 0.0f;
    float L_attn = 0.5f * L_attn_gat + 0.5f * L_attn_rule;
    float L_reg  = acc[6];
    float L_total = 1.0f * L_recon + 0.5f * L_rule + 0.3f * L_attn + 1e-4f * L_reg;
    out[0] = L_total;
    out[1] = L_recon;
    out[2] = L_rule;
    out[3] = L_attn;
    out[4] = L_attn_gat;
    out[5] = L_attn_rule;
    out[6] = L_reg;
    out[7] = vc;
}

extern "C" void kernel_launch(void* const* d_in, const int* in_sizes, int n_in,
                              void* d_out, int out_size, void* d_ws, size_t ws_size,
                              hipStream_t stream) {
    const float* model_scores = (const float*)d_in[0];
    const float* rule_scores  = (const float*)d_in[1];
    const float* alpha_gat    = (const float*)d_in[2];
    const float* beta_rule    = (const float*)d_in[3];
    const int*   edge_index   = (const int*)d_in[4];   // [2, E]: src then dst
    const int*   entity_types = (const int*)d_in[5];
    const float* param0       = (const float*)d_in[6];
    const float* param1       = (const float*)d_in[7];
    float* out = (float*)d_out;

    float* acc    = (float*)d_ws;
    int*   segmax = (int*)d_ws + 8;   // 32B offset: int4-aligned

    const int* src = edge_index;
    const int* dst = edge_index + NE;

    init_kernel<<<(N_CAR / 4 + 255) / 256, 256, 0, stream>>>(acc, (int4*)segmax);
    mega_kernel<<<MEGA_GRID, 256, 0, stream>>>((const int4*)src, (const int4*)dst,
                                               entity_types, (const float4*)alpha_gat,
                                               segmax, (const float4*)param0,
                                               (const float4*)param1, acc);
    car_kernel<<<(N_CAR + 255) / 256, 256, 0, stream>>>(model_scores, rule_scores,
                                                        beta_rule, segmax, acc);
    finalize_kernel<<<1, 64, 0, stream>>>(acc, out);
}